// Round 1
// baseline (511.884 us; speedup 1.0000x reference)
//
#include <hip/hip_runtime.h>

#define B_   8
#define S_   2048
#define IN_  96
#define H_   256

typedef float f32x4 __attribute__((ext_vector_type(4)));
typedef short bf16x8 __attribute__((ext_vector_type(8)));   // 8 bf16 in 4 VGPRs

__device__ __forceinline__ unsigned short f2bf(float x) {
    unsigned int u = __float_as_uint(x);
    u += 0x7fffu + ((u >> 16) & 1u);          // round-nearest-even
    return (unsigned short)(u >> 16);
}

// ---------------------------------------------------------------------------
// Kernel 1: fused QKV projection. fp32 math, bf16 outputs.
//   qp[b][s][h], kp[b][s][h] row-major; vt[b][h][s] transposed (for PV B-frags)
// ---------------------------------------------------------------------------
__global__ __launch_bounds__(256) void proj_kernel(
    const float* __restrict__ query, const float* __restrict__ key,
    const float* __restrict__ value,
    const float* __restrict__ Wq, const float* __restrict__ bq,
    const float* __restrict__ Wk, const float* __restrict__ bk,
    const float* __restrict__ Wv, const float* __restrict__ bv,
    unsigned short* __restrict__ qp, unsigned short* __restrict__ kp,
    unsigned short* __restrict__ vt)
{
    __shared__ float in_lds[3][IN_][20];      // [proj][f][row], pad 20 for banks/align
    const int t  = threadIdx.x;
    const int s0 = blockIdx.x * 16;           // 16 rows per block
    const int b  = s0 / S_;
    const int sl = s0 % S_;

    const float* srcs[3] = { query + (size_t)s0 * IN_,
                             key   + (size_t)s0 * IN_,
                             value + (size_t)s0 * IN_ };
    #pragma unroll
    for (int p = 0; p < 3; ++p) {
        #pragma unroll
        for (int i = 0; i < 6; ++i) {
            int idx = i * 256 + t;            // 0..1535, coalesced
            int r = idx / IN_;
            int f = idx - r * IN_;
            in_lds[p][f][r] = srcs[p][idx];
        }
    }
    __syncthreads();

    const int h = t;                          // one output column per thread
    const float* Ws[3] = { Wq, Wk, Wv };
    const float* bs[3] = { bq, bk, bv };

    #pragma unroll
    for (int p = 0; p < 3; ++p) {
        float bias = bs[p][h];
        float acc[16];
        #pragma unroll
        for (int r = 0; r < 16; ++r) acc[r] = bias;
        for (int f = 0; f < IN_; ++f) {
            float w = Ws[p][f * H_ + h];      // coalesced, L2-resident
            const float* row = &in_lds[p][f][0];
            #pragma unroll
            for (int r = 0; r < 16; ++r) acc[r] = fmaf(row[r], w, acc[r]);
        }
        if (p == 0) {
            #pragma unroll
            for (int r = 0; r < 16; ++r)
                qp[(size_t)(s0 + r) * H_ + h] = f2bf(acc[r]);
        } else if (p == 1) {
            #pragma unroll
            for (int r = 0; r < 16; ++r)
                kp[(size_t)(s0 + r) * H_ + h] = f2bf(acc[r]);
        } else {
            #pragma unroll
            for (int r = 0; r < 16; r += 2) {
                unsigned int pk = (unsigned int)f2bf(acc[r]) |
                                  ((unsigned int)f2bf(acc[r + 1]) << 16);
                *(unsigned int*)&vt[((size_t)b * H_ + h) * S_ + sl + r] = pk;
            }
        }
    }
}

// ---------------------------------------------------------------------------
// Kernel 2: flash attention (online softmax) + LayerNorm, fused.
// Block = 128 thr = 2 waves, one 16-row Q strip; waves split keys even/odd
// 64-tiles and merge at the end. S^T = mfma(K_frag, Q_frag) so softmax stats
// are per-lane (q = lane&15) and P transposes through per-wave-private LDS.
// ---------------------------------------------------------------------------
__global__ __launch_bounds__(128) void attn_kernel(
    const unsigned short* __restrict__ qp, const unsigned short* __restrict__ kp,
    const unsigned short* __restrict__ vt, const int* __restrict__ mask,
    const float* __restrict__ gamma, const float* __restrict__ beta,
    float* __restrict__ out)
{
    __shared__ unsigned short P_lds[2][16][72];   // pitch 72 elems (144B) vs banks
    __shared__ float mbuf[2][16], lbuf[2][16];
    __shared__ float Obuf[16][264];               // merge buffer

    const int tid  = threadIdx.x;
    const int wave = tid >> 6;
    const int lane = tid & 63;
    const int col  = lane & 15;                   // q index within strip
    const int quad = lane >> 4;

    const int strip = blockIdx.x;                 // 0..1023
    const int b  = strip >> 7;
    const int q0 = (strip & 127) << 4;

    // Q B-fragments, kept in registers for the whole kernel.
    // B[k=quad*8+j + 32*s][n=col] = Q[q0+col][quad*8+j+32*s]
    const unsigned short* qbase = qp + (size_t)(b * S_ + q0 + col) * H_ + quad * 8;
    bf16x8 qf[8];
    #pragma unroll
    for (int s = 0; s < 8; ++s) qf[s] = *(const bf16x8*)(qbase + s * 32);

    f32x4 O[16];
    #pragma unroll
    for (int ht = 0; ht < 16; ++ht) O[ht] = (f32x4)(0.0f);
    float m = -1e30f, l = 0.0f;

    const unsigned short* kbase = kp + (size_t)(b * S_ + col) * H_ + quad * 8;
    const unsigned short* vbase = vt + (size_t)(b * H_ + col) * S_ + quad * 8;
    const int* mbase = mask + (size_t)(b * S_ + q0 + col) * S_ + quad * 4;
    unsigned short* Prow = &P_lds[wave][col][0];

    for (int kb = wave * 64; kb < S_; kb += 128) {
        // mask prefetch: int4 == keys {quad*4 + r} of tile mt
        int4 msk[4];
        #pragma unroll
        for (int mt = 0; mt < 4; ++mt)
            msk[mt] = *(const int4*)(mbase + kb + mt * 16);

        // ---- S^T = K · Q^T  (row = key, col = q) ----
        f32x4 St[4];
        #pragma unroll
        for (int mt = 0; mt < 4; ++mt) St[mt] = (f32x4)(0.0f);
        #pragma unroll
        for (int s = 0; s < 8; ++s) {
            #pragma unroll
            for (int mt = 0; mt < 4; ++mt) {
                bf16x8 kf = *(const bf16x8*)(kbase + (size_t)(kb + mt * 16) * H_ + s * 32);
                St[mt] = __builtin_amdgcn_mfma_f32_16x16x32_bf16(kf, qf[s], St[mt], 0, 0, 0);
            }
        }

        // ---- scale + mask + online softmax (stats per lane, q = col) ----
        float sc[4][4];
        float mloc = -1e30f;
        #pragma unroll
        for (int mt = 0; mt < 4; ++mt) {
            int mv[4] = { msk[mt].x, msk[mt].y, msk[mt].z, msk[mt].w };
            #pragma unroll
            for (int r = 0; r < 4; ++r) {
                float x = St[mt][r] * 0.0625f;          // / sqrt(256)
                x = (mv[r] == 0) ? -1e10f : x;
                sc[mt][r] = x;
                mloc = fmaxf(mloc, x);
            }
        }
        mloc = fmaxf(mloc, __shfl_xor(mloc, 16));
        mloc = fmaxf(mloc, __shfl_xor(mloc, 32));
        float mnew  = fmaxf(m, mloc);
        float alpha = __expf(m - mnew);
        float ps = 0.0f;
        #pragma unroll
        for (int mt = 0; mt < 4; ++mt) {
            unsigned long long pk64 = 0;
            #pragma unroll
            for (int r = 0; r < 4; ++r) {
                float p = __expf(sc[mt][r] - mnew);
                ps += p;
                pk64 |= (unsigned long long)f2bf(p) << (16 * r);
            }
            // P_lds[q=col][key = mt*16 + quad*4 + r]
            *(unsigned long long*)&Prow[mt * 16 + quad * 4] = pk64;
        }
        ps += __shfl_xor(ps, 16);
        ps += __shfl_xor(ps, 32);
        l = l * alpha + ps;
        m = mnew;

        // rescale O (rows are q = quad*4+r -> fetch alpha of that q)
        float a4[4];
        #pragma unroll
        for (int r = 0; r < 4; ++r) a4[r] = __shfl(alpha, quad * 4 + r);
        #pragma unroll
        for (int ht = 0; ht < 16; ++ht) {
            O[ht][0] *= a4[0]; O[ht][1] *= a4[1];
            O[ht][2] *= a4[2]; O[ht][3] *= a4[3];
        }

        // ---- O += P · V ----
        #pragma unroll
        for (int s2 = 0; s2 < 2; ++s2) {
            bf16x8 pf = *(const bf16x8*)&Prow[s2 * 32 + quad * 8];  // A[m=col][k]
            #pragma unroll
            for (int ht = 0; ht < 16; ++ht) {
                bf16x8 vf = *(const bf16x8*)(vbase + (size_t)ht * 16 * S_ + kb + s2 * 32);
                O[ht] = __builtin_amdgcn_mfma_f32_16x16x32_bf16(pf, vf, O[ht], 0, 0, 0);
            }
        }
    }

    // ---- cross-wave merge (keys were split) ----
    if (lane < 16) { mbuf[wave][lane] = m; lbuf[wave][lane] = l; }
    __syncthreads();
    float m0 = mbuf[0][col], m1 = mbuf[1][col];
    float mm = fmaxf(m0, m1);
    float a0 = __expf(m0 - mm), a1 = __expf(m1 - mm);
    float ltot = lbuf[0][col] * a0 + lbuf[1][col] * a1;
    float aw = (wave == 0) ? a0 : a1;
    float awr[4];
    #pragma unroll
    for (int r = 0; r < 4; ++r) awr[r] = __shfl(aw, quad * 4 + r);

    if (wave == 1) {
        #pragma unroll
        for (int ht = 0; ht < 16; ++ht)
            #pragma unroll
            for (int r = 0; r < 4; ++r)
                Obuf[quad * 4 + r][ht * 16 + col] = O[ht][r] * awr[r];
    }
    __syncthreads();

    if (wave == 0) {
        float lr[4];
        #pragma unroll
        for (int r = 0; r < 4; ++r) lr[r] = __shfl(ltot, quad * 4 + r);
        #pragma unroll
        for (int ht = 0; ht < 16; ++ht)
            #pragma unroll
            for (int r = 0; r < 4; ++r)
                O[ht][r] = (O[ht][r] * awr[r] + Obuf[quad * 4 + r][ht * 16 + col]) / lr[r];

        // ---- LayerNorm over h (256) per q row ----
        float sum[4] = {0.f, 0.f, 0.f, 0.f};
        #pragma unroll
        for (int ht = 0; ht < 16; ++ht)
            #pragma unroll
            for (int r = 0; r < 4; ++r) sum[r] += O[ht][r];
        #pragma unroll
        for (int r = 0; r < 4; ++r) {
            sum[r] += __shfl_xor(sum[r], 1);
            sum[r] += __shfl_xor(sum[r], 2);
            sum[r] += __shfl_xor(sum[r], 4);
            sum[r] += __shfl_xor(sum[r], 8);
        }
        float mu[4];
        #pragma unroll
        for (int r = 0; r < 4; ++r) mu[r] = sum[r] * (1.0f / H_);
        float sq[4] = {0.f, 0.f, 0.f, 0.f};
        #pragma unroll
        for (int ht = 0; ht < 16; ++ht)
            #pragma unroll
            for (int r = 0; r < 4; ++r) {
                float d = O[ht][r] - mu[r];
                sq[r] += d * d;
            }
        #pragma unroll
        for (int r = 0; r < 4; ++r) {
            sq[r] += __shfl_xor(sq[r], 1);
            sq[r] += __shfl_xor(sq[r], 2);
            sq[r] += __shfl_xor(sq[r], 4);
            sq[r] += __shfl_xor(sq[r], 8);
        }
        float rstd[4];
        #pragma unroll
        for (int r = 0; r < 4; ++r) rstd[r] = rsqrtf(sq[r] * (1.0f / H_) + 1e-6f);

        #pragma unroll
        for (int ht = 0; ht < 16; ++ht) {
            float g  = gamma[ht * 16 + col];
            float be = beta[ht * 16 + col];
            #pragma unroll
            for (int r = 0; r < 4; ++r) {
                size_t idx = (size_t)(b * S_ + q0 + quad * 4 + r) * H_ + ht * 16 + col;
                out[idx] = (O[ht][r] - mu[r]) * rstd[r] * g + be;
            }
        }
    }
}

// ---------------------------------------------------------------------------
extern "C" void kernel_launch(void* const* d_in, const int* in_sizes, int n_in,
                              void* d_out, int out_size, void* d_ws, size_t ws_size,
                              hipStream_t stream)
{
    const float* query = (const float*)d_in[0];
    const float* key   = (const float*)d_in[1];
    const float* value = (const float*)d_in[2];
    const int*   mask  = (const int*)d_in[3];
    const float* Wq = (const float*)d_in[4];
    const float* bq = (const float*)d_in[5];
    const float* Wk = (const float*)d_in[6];
    const float* bk = (const float*)d_in[7];
    const float* Wv = (const float*)d_in[8];
    const float* bv = (const float*)d_in[9];
    const float* gamma = (const float*)d_in[10];
    const float* beta  = (const float*)d_in[11];
    float* out = (float*)d_out;

    unsigned short* qp = (unsigned short*)d_ws;          // [8][2048][256] bf16
    unsigned short* kp = qp + (size_t)B_ * S_ * H_;      // [8][2048][256] bf16
    unsigned short* vt = kp + (size_t)B_ * S_ * H_;      // [8][256][2048] bf16

    proj_kernel<<<B_ * S_ / 16, 256, 0, stream>>>(query, key, value,
                                                  Wq, bq, Wk, bk, Wv, bv,
                                                  qp, kp, vt);
    attn_kernel<<<B_ * S_ / 16, 128, 0, stream>>>(qp, kp, vt, mask, gamma, beta, out);
}